// Round 9
// baseline (1890.201 us; speedup 1.0000x reference)
//
#include <hip/hip_runtime.h>
#include <stdint.h>

// Problem constants: B=4, S=4096, E=256
#define SEQ   4096
#define EMB   256
#define NROW  16384   // B*S

typedef short s16x8  __attribute__((ext_vector_type(8)));
typedef float f32x4  __attribute__((ext_vector_type(4)));
typedef float f32x16 __attribute__((ext_vector_type(16)));
typedef unsigned int u32;

#define LOG2E 1.44269504088896340736f
#define RESCALE_THR 8.0f

__device__ __forceinline__ unsigned short f2bf(float f) {
    unsigned int u = __builtin_bit_cast(unsigned int, f);
    u += 0x7FFFu + ((u >> 16) & 1u);   // RNE
    return (unsigned short)(u >> 16);
}
__device__ __forceinline__ u32 pkbf2(float lo, float hi) {
    return (u32)f2bf(lo) | ((u32)f2bf(hi) << 16);
}
__device__ __forceinline__ unsigned short f2h(float f) {
    _Float16 h = (_Float16)f;
    return __builtin_bit_cast(unsigned short, h);
}
__device__ __forceinline__ float h2f(unsigned short u) {
    return (float)__builtin_bit_cast(_Float16, u);
}

// global -> LDS direct (16B per lane, linear dest).
typedef __attribute__((address_space(3))) u32 lds_u32;
typedef __attribute__((address_space(1))) const u32 glb_u32;
__device__ __forceinline__ void gload16(const unsigned short* g, const unsigned short* l) {
    __builtin_amdgcn_global_load_lds((glb_u32*)(uintptr_t)g,
                                     (lds_u32*)(u32)(uintptr_t)l, 16, 0, 0);
}

#define FENCE() __asm__ volatile("" ::: "memory")

// ---------------------------------------------------------------------------
// Kernel 0: convert x and Wq/Wk/Wv fp32 -> bf16 once.
// ---------------------------------------------------------------------------
__global__ __launch_bounds__(256, 8) void xcvt_kernel(
    const float* __restrict__ x, const float* __restrict__ Wq,
    const float* __restrict__ Wk, const float* __restrict__ Wv,
    unsigned short* __restrict__ xb, unsigned short* __restrict__ Wb)
{
    const int gid = blockIdx.x*256 + threadIdx.x;
    const float* src;
    unsigned short* dst;
    size_t off;
    if (gid < 524288) {                 // x: 4,194,304 elems
        src = x; dst = xb; off = (size_t)gid * 8;
    } else {                            // W: 3 x 65,536 elems
        size_t wi = (size_t)(gid - 524288) * 8;
        int w = (int)(wi >> 16);
        off = wi & 65535;
        src = (w == 0) ? Wq : (w == 1) ? Wk : Wv;
        dst = Wb + (size_t)w * 65536;
    }
    const float4 v0 = *(const float4*)(src + off);
    const float4 v1 = *(const float4*)(src + off + 4);
    union { unsigned short u[8]; s16x8 v; } o;
    o.u[0]=f2bf(v0.x); o.u[1]=f2bf(v0.y); o.u[2]=f2bf(v0.z); o.u[3]=f2bf(v0.w);
    o.u[4]=f2bf(v1.x); o.u[5]=f2bf(v1.y); o.u[6]=f2bf(v1.z); o.u[7]=f2bf(v1.w);
    *(s16x8*)(dst + off) = o.v;
}

// ---------------------------------------------------------------------------
// Kernel 1: QKV projection (bf16 in, bf16 out).  Grid 512; 2 blocks/CU.
// ---------------------------------------------------------------------------
#define PWSTR 264

__global__ __launch_bounds__(256, 2) void proj_kernel(
    const unsigned short* __restrict__ xb, const unsigned short* __restrict__ Wb,
    unsigned short* __restrict__ Qb, unsigned short* __restrict__ Kb,
    unsigned short* __restrict__ Vt)
{
    __shared__ unsigned short Wl[3][32][PWSTR];  // 50688 B
    __shared__ unsigned short QKs[2][64][40];    // 10240 B
    __shared__ unsigned short Vtr[32][72];       //  4608 B
    const int bid = blockIdx.x;
    const int ct  = bid >> 6;   // 0..7: 32 out-cols
    const int rb  = bid & 63;   // 256-row group
    const int t   = threadIdx.x;

    {   // stage 32x256 bf16 chunk of each W
        const int o = t >> 3, seg = t & 7;
        #pragma unroll
        for (int w = 0; w < 3; ++w) {
            const unsigned short* src = Wb + (size_t)w*65536 + (ct*32 + o)*256 + seg*32;
            #pragma unroll
            for (int i = 0; i < 4; ++i)
                *(s16x8*)&Wl[w][o][seg*32 + i*8] = *(const s16x8*)(src + i*8);
        }
    }
    __syncthreads();

    const int wave = t >> 6, lane = t & 63;
    const int g = lane >> 4, lr = lane & 15;

    for (int it = 0; it < 4; ++it) {
        const int rowblk = rb*256 + it*64;
        const int rowbase = rowblk + wave*16;
        s16x8 a[8];
        {
            const unsigned short* xr = xb + (size_t)(rowbase + lr)*256;
            #pragma unroll
            for (int c = 0; c < 8; ++c)
                a[c] = *(const s16x8*)(xr + c*32 + g*8);
        }
        f32x4 acc[3][2];
        #pragma unroll
        for (int w = 0; w < 3; ++w)
            #pragma unroll
            for (int cf = 0; cf < 2; ++cf)
                #pragma unroll
                for (int j = 0; j < 4; ++j) acc[w][cf][j] = 0.0f;

        #pragma unroll
        for (int w = 0; w < 3; ++w)
            #pragma unroll
            for (int cf = 0; cf < 2; ++cf)
                #pragma unroll
                for (int c = 0; c < 8; ++c) {
                    s16x8 bfr = *(const s16x8*)&Wl[w][cf*16 + lr][c*32 + g*8];
                    acc[w][cf] = __builtin_amdgcn_mfma_f32_16x16x32_bf16(a[c], bfr, acc[w][cf], 0, 0, 0);
                }

        __syncthreads();
        #pragma unroll
        for (int cf = 0; cf < 2; ++cf) {
            #pragma unroll
            for (int j = 0; j < 4; ++j) {
                const int row = wave*16 + g*4 + j;
                QKs[0][row][cf*16 + lr] = f2bf(acc[0][cf][j] * 0.0625f);  // fold 1/sqrt(256)
                QKs[1][row][cf*16 + lr] = f2bf(acc[1][cf][j]);
            }
            ushort4 pv;
            pv.x = f2bf(acc[2][cf][0]); pv.y = f2bf(acc[2][cf][1]);
            pv.z = f2bf(acc[2][cf][2]); pv.w = f2bf(acc[2][cf][3]);
            *(ushort4*)&Vtr[cf*16 + lr][wave*16 + g*4] = pv;
        }
        __syncthreads();
        {   // coalesced b128 stores
            const int row = t >> 2, cs = t & 3;
            *(s16x8*)&Qb[(size_t)(rowblk + row)*256 + ct*32 + cs*8] = *(const s16x8*)&QKs[0][row][cs*8];
            *(s16x8*)&Kb[(size_t)(rowblk + row)*256 + ct*32 + cs*8] = *(const s16x8*)&QKs[1][row][cs*8];
            const int colL = t >> 3, seg = t & 7;
            const int bb = rowblk >> 12, ss0 = rowblk & 4095;
            *(s16x8*)&Vt[((size_t)(bb*256 + ct*32 + colL))*4096 + ss0 + seg*8] = *(const s16x8*)&Vtr[colL][seg*8];
        }
    }
}

// ---------------------------------------------------------------------------
// Kernel 2: flash attention, split-KV H=4.  Grid 512 = 16 (b,h) XCD-pinned
// groups x 32 q-tiles(128).  512 threads = 8 waves (4 qh x 2 kvh); 64KB LDS ->
// 2 blocks/CU (16 waves/CU).  Single K buf + single V buf, rotating T3/T4
// schedule: loads for the next phase always in flight under the current MFMA
// phase (counted vmcnt(4), never 0 mid-loop).  In-block kvh merge; per-block
// partials (normalized f16 O + m,l) -> 4-way combine kernel.
// ---------------------------------------------------------------------------
#define AKVB 64
#define ANT  16          // 1024 kv per block / 64

__global__ __launch_bounds__(512, 4) void attn_kernel(
    const unsigned short* __restrict__ Qb, const unsigned short* __restrict__ Kb,
    const unsigned short* __restrict__ Vt, unsigned short* __restrict__ pob,
    float* __restrict__ pm, float* __restrict__ pl)
{
    __shared__ unsigned short KV[32768];   // K: [64][256] @0 ; V: [256][64] @16384 (elems)
    __shared__ float All[8][32];
    __shared__ float MrgM[128], MrgL[128], Wt1[128], Wt2[128];

    const int bid = blockIdx.x;
    const int grp = bid & 15;                // grp&7 = XCD pin (2 groups/XCD)
    const int b = grp >> 2, h = grp & 3;
    const int qt = bid >> 4;
    const int t = threadIdx.x;
    const int w = t >> 6, lane = t & 63;
    const int h8 = lane >> 5, lr5 = lane & 31;
    const int qh = w >> 1, kvh = w & 1;
    const int kv0 = h * 1024;
    const int rowbase = b*4096 + qt*128 + qh*32;

    const unsigned short* Kg = Kb + (size_t)b*4096*256;
    const unsigned short* Vg = Vt + (size_t)b*256*4096;

    // Q B-fragments: col = q = lr5, k = mi*16 + h8*8 + j
    s16x8 qa[16];
    {
        const unsigned short* qp = Qb + (size_t)(rowbase + lr5)*256;
        #pragma unroll
        for (int mi = 0; mi < 16; ++mi)
            qa[mi] = *(const s16x8*)(qp + mi*16 + h8*8);
    }

    f32x16 acc[8];
    #pragma unroll
    for (int cc = 0; cc < 8; ++cc)
        #pragma unroll
        for (int r = 0; r < 16; ++r) acc[cc][r] = 0.0f;
    float m = -__builtin_inff(), l = 0.0f;   // per-lane state for q = lr5

    auto stageK = [&](int kt2) {
        const int kvb = kv0 + kt2*AKVB;
        #pragma unroll
        for (int i = 0; i < 4; ++i) {
            const int idx = i*512 + t;
            const int kr = idx >> 5, ks = idx & 31;          // 64 rows x 32 slots
            gload16(Kg + (size_t)(kvb + kr)*256 + ((ks ^ (kr & 31)) << 3),
                    &KV[idx << 3]);
        }
    };
    auto stageV = [&](int kt2) {
        const int kvb = kv0 + kt2*AKVB;
        #pragma unroll
        for (int i = 0; i < 4; ++i) {
            const int idx = i*512 + t;
            const int vr = idx >> 3, vs = idx & 7;           // 256 rows x 8 slots
            gload16(Vg + (size_t)vr*4096 + kvb + ((vs ^ (vr & 7)) << 3),
                    &KV[16384 + (idx << 3)]);
        }
    };

    stageK(0);
    stageV(0);

    for (int kt = 0; kt < ANT; ++kt) {
        const bool last = (kt == ANT - 1);

        // wait own K(kt) loads (V(kt) stays in flight), sync all waves
        __asm__ volatile("s_waitcnt vmcnt(4)" ::: "memory");
        __builtin_amdgcn_s_barrier();
        FENCE();

        // Swapped QK^T: A = K rows, B = Q.  C: col=q=lr5, row=kv=(r&3)+8(r>>2)+4h8.
        const int krow = kvh*32 + lr5;
        const int ksw = krow & 31;
        f32x16 sc;
        #pragma unroll
        for (int r = 0; r < 16; ++r) sc[r] = 0.0f;
        __builtin_amdgcn_s_setprio(1);
        #pragma unroll
        for (int mi = 0; mi < 16; ++mi) {
            const int slot = (2*mi + h8) ^ ksw;
            s16x8 kf = *(const s16x8*)&KV[krow*256 + slot*8];
            sc = __builtin_amdgcn_mfma_f32_32x32x16_bf16(kf, qa[mi], sc, 0, 0, 0);
        }
        __builtin_amdgcn_s_setprio(0);

        // all waves done reading K buf -> start refilling it
        __builtin_amdgcn_s_barrier();
        FENCE();
        if (!last) stageK(kt + 1);

        // softmax overlaps the K(kt+1)/V(kt) flight
        float x0 = fmaxf(sc[0],  sc[1]),  x1 = fmaxf(sc[2],  sc[3]);
        float x2 = fmaxf(sc[4],  sc[5]),  x3 = fmaxf(sc[6],  sc[7]);
        float x4 = fmaxf(sc[8],  sc[9]),  x5 = fmaxf(sc[10], sc[11]);
        float x6 = fmaxf(sc[12], sc[13]), x7 = fmaxf(sc[14], sc[15]);
        x0 = fmaxf(x0, x1); x2 = fmaxf(x2, x3); x4 = fmaxf(x4, x5); x6 = fmaxf(x6, x7);
        float pmax = fmaxf(fmaxf(x0, x2), fmaxf(x4, x6));
        pmax = fmaxf(pmax, __shfl_xor(pmax, 32));

        if (!__all(pmax - m <= RESCALE_THR)) {
            const float mn = fmaxf(m, pmax);
            const float al = __builtin_amdgcn_exp2f((m - mn) * LOG2E);
            m = mn; l *= al;
            if (lane < 32) All[w][lr5] = al;     // bridge q-col -> q-row layout
            #pragma unroll
            for (int rr = 0; rr < 4; ++rr) {
                f32x4 a4 = *(const f32x4*)&All[w][rr*8 + 4*h8];
                #pragma unroll
                for (int rj = 0; rj < 4; ++rj)
                    #pragma unroll
                    for (int cc = 0; cc < 8; ++cc) acc[cc][rr*4 + rj] *= a4[rj];
            }
        }

        #pragma unroll
        for (int r = 0; r < 16; ++r) sc[r] = __builtin_amdgcn_exp2f((sc[r] - m) * LOG2E);
        float ps = ((sc[0]+sc[1]) + (sc[2]+sc[3])) + ((sc[4]+sc[5]) + (sc[6]+sc[7]))
                 + ((sc[8]+sc[9]) + (sc[10]+sc[11])) + ((sc[12]+sc[13]) + (sc[14]+sc[15]));
        ps += __shfl_xor(ps, 32);
        l += ps;

        // P -> A-fragments in-register (half-exchange via shfl_xor 32)
        const u32 dw0 = pkbf2(sc[0],  sc[1]),  dw1 = pkbf2(sc[2],  sc[3]);
        const u32 dw2 = pkbf2(sc[4],  sc[5]),  dw3 = pkbf2(sc[6],  sc[7]);
        const u32 dw4 = pkbf2(sc[8],  sc[9]),  dw5 = pkbf2(sc[10], sc[11]);
        const u32 dw6 = pkbf2(sc[12], sc[13]), dw7 = pkbf2(sc[14], sc[15]);
        const bool hi = (h8 != 0);
        const u32 s10 = __shfl_xor(hi ? dw0 : dw2, 32);
        const u32 s11 = __shfl_xor(hi ? dw1 : dw3, 32);
        const u32 s20 = __shfl_xor(hi ? dw4 : dw6, 32);
        const u32 s21 = __shfl_xor(hi ? dw5 : dw7, 32);
        union { u32 u[4]; s16x8 v; } pa1, pa2;
        pa1.u[0] = hi ? s10 : dw0;  pa1.u[1] = hi ? s11 : dw1;
        pa1.u[2] = hi ? dw2 : s10;  pa1.u[3] = hi ? dw3 : s11;
        pa2.u[0] = hi ? s20 : dw4;  pa2.u[1] = hi ? s21 : dw5;
        pa2.u[2] = hi ? dw6 : s20;  pa2.u[3] = hi ? dw7 : s21;

        // wait own V(kt) loads (K(kt+1) stays in flight), sync
        if (!last) { __asm__ volatile("s_waitcnt vmcnt(4)" ::: "memory"); }
        else       { __asm__ volatile("s_waitcnt vmcnt(0)" ::: "memory"); }
        __builtin_amdgcn_s_barrier();
        FENCE();

        // PV: out[32q][256d] += P[32q x 32kv] * V[32kv x d]
        __builtin_amdgcn_s_setprio(1);
        #pragma unroll
        for (int cc = 0; cc < 8; ++cc) {
            const int vrow = cc*32 + lr5;
            const int vsw = vrow & 7;
            s16x8 v1 = *(const s16x8*)&KV[16384 + vrow*64 + (((4*kvh + h8)     ^ vsw) << 3)];
            s16x8 v2 = *(const s16x8*)&KV[16384 + vrow*64 + (((4*kvh + 2 + h8) ^ vsw) << 3)];
            acc[cc] = __builtin_amdgcn_mfma_f32_32x32x16_bf16(pa1.v, v1, acc[cc], 0, 0, 0);
            acc[cc] = __builtin_amdgcn_mfma_f32_32x32x16_bf16(pa2.v, v2, acc[cc], 0, 0, 0);
        }
        __builtin_amdgcn_s_setprio(0);

        if (!last) {            // all done reading V buf -> refill it
            __builtin_amdgcn_s_barrier();
            FENCE();
            stageV(kt + 1);
        }
    }

    // ---- in-block merge of kvh halves (reuse KV as [64][256] f32, 2 chunks) ----
    __syncthreads();
    float* Mrg = (float*)&KV[0];
    for (int half = 0; half < 2; ++half) {
        if (kvh == 1 && (qh >> 1) == half) {
            const int qs = (qh & 1) << 5;
            #pragma unroll
            for (int cc = 0; cc < 8; ++cc)
                #pragma unroll
                for (int r = 0; r < 16; ++r) {
                    const int qr = (r & 3) + 8*(r >> 2) + 4*h8;
                    Mrg[(qs + qr)*256 + cc*32 + lr5] = acc[cc][r];
                }
            if (lane < 32) { MrgM[qh*32 + lr5] = m; MrgL[qh*32 + lr5] = l; }
        }
        __syncthreads();
        if (kvh == 0 && (qh >> 1) == half) {
            const int qs = (qh & 1) << 5;
            const float m2 = MrgM[qh*32 + lr5], l2 = MrgL[qh*32 + lr5];
            const float M  = fmaxf(m, m2);
            const float w1 = __builtin_amdgcn_exp2f((m  - M) * LOG2E);
            const float w2 = __builtin_amdgcn_exp2f((m2 - M) * LOG2E);
            const float L  = l*w1 + l2*w2;
            const float r1 = w1 / L, r2 = w2 / L;
            if (lane < 32) {
                Wt1[qh*32 + lr5] = r1; Wt2[qh*32 + lr5] = r2;
                pm[(size_t)h*NROW + rowbase + lr5] = M;
                pl[(size_t)h*NROW + rowbase + lr5] = L;
            }
            unsigned short* pd = pob + (size_t)h*NROW*256;
            #pragma unroll
            for (int rr = 0; rr < 4; ++rr) {
                f32x4 r1q = *(const f32x4*)&Wt1[qh*32 + rr*8 + 4*h8];
                f32x4 r2q = *(const f32x4*)&Wt2[qh*32 + rr*8 + 4*h8];
                #pragma unroll
                for (int rj = 0; rj < 4; ++rj) {
                    const int qr = rj + 8*rr + 4*h8;
                    #pragma unroll
                    for (int cc = 0; cc < 8; ++cc) {
                        const float v = acc[cc][rr*4 + rj]*r1q[rj]
                                      + Mrg[(qs + qr)*256 + cc*32 + lr5]*r2q[rj];
                        pd[(size_t)(rowbase + qr)*256 + cc*32 + lr5] = f2h(v);
                    }
                }
            }
        }
        __syncthreads();
    }
}

// ---------------------------------------------------------------------------
// Kernel 3: combine the four KV-quarter partials (normalized f16 O + m,l).
// ---------------------------------------------------------------------------
__global__ __launch_bounds__(256, 8) void combine_kernel(
    const unsigned short* __restrict__ pob, const float* __restrict__ pm,
    const float* __restrict__ pl, float* __restrict__ out)
{
    const int idx = blockIdx.x*256 + threadIdx.x;   // grid 2048 -> 524288 threads
    const int row = idx >> 5;
    const int d8 = (idx & 31) << 3;
    const float M = fmaxf(fmaxf(pm[row], pm[NROW + row]),
                          fmaxf(pm[2*NROW + row], pm[3*NROW + row]));
    float o[8] = {0,0,0,0,0,0,0,0};
    float wsum = 0.0f;
    #pragma unroll
    for (int i = 0; i < 4; ++i) {
        const float wgt = __builtin_amdgcn_exp2f((pm[i*NROW + row] - M) * LOG2E)
                        * pl[i*NROW + row];
        wsum += wgt;
        s16x8 v = *(const s16x8*)(pob + (size_t)i*NROW*256 + (size_t)row*256 + d8);
        #pragma unroll
        for (int j = 0; j < 8; ++j)
            o[j] += wgt * h2f((unsigned short)v[j]);
    }
    const float r = 1.0f / wsum;
    float4 o0 = {o[0]*r, o[1]*r, o[2]*r, o[3]*r};
    float4 o1 = {o[4]*r, o[5]*r, o[6]*r, o[7]*r};
    *(float4*)(out + (size_t)row*256 + d8)     = o0;
    *(float4*)(out + (size_t)row*256 + d8 + 4) = o1;
}

// ---------------------------------------------------------------------------
extern "C" void kernel_launch(void* const* d_in, const int* in_sizes, int n_in,
                              void* d_out, int out_size, void* d_ws, size_t ws_size,
                              hipStream_t stream) {
    const float* x  = (const float*)d_in[0];
    const float* Wq = (const float*)d_in[1];
    const float* Wk = (const float*)d_in[2];
    const float* Wv = (const float*)d_in[3];

    unsigned short* Qb  = (unsigned short*)d_ws;         // 8 MB
    unsigned short* Kb  = Qb + (size_t)NROW*EMB;         // 8 MB
    unsigned short* Vt  = Kb + (size_t)NROW*EMB;         // 8 MB, [b][d][s]
    unsigned short* pob = Vt + (size_t)NROW*EMB;         // 32 MB, f16 [4][NROW][256]
    float* pm = (float*)(pob + (size_t)4*NROW*EMB);      // 256 KB
    float* pl = pm + (size_t)4*NROW;                     // 256 KB  (total ~56.5 MB)
    // xb (8.4MB) + Wb alias pob (dead after proj; pob written by attn)
    unsigned short* xb = pob;
    unsigned short* Wb = xb + (size_t)NROW*EMB;

    xcvt_kernel<<<2144, 256, 0, stream>>>(x, Wq, Wk, Wv, xb, Wb);
    proj_kernel<<<512, 256, 0, stream>>>(xb, Wb, Qb, Kb, Vt);
    attn_kernel<<<512, 512, 0, stream>>>(Qb, Kb, Vt, pob, pm, pl);
    combine_kernel<<<2048, 256, 0, stream>>>(pob, pm, pl, (float*)d_out);
}

// Round 10
// 237.287 us; speedup vs baseline: 7.9659x; 7.9659x over previous
//
#include <hip/hip_runtime.h>
#include <stdint.h>

// Problem constants: B=4, S=4096, E=256
#define SEQ   4096
#define EMB   256
#define NROW  16384   // B*S

typedef short s16x8  __attribute__((ext_vector_type(8)));
typedef float f32x4  __attribute__((ext_vector_type(4)));
typedef float f32x16 __attribute__((ext_vector_type(16)));
typedef unsigned int u32;

#define LOG2E 1.44269504088896340736f
#define RESCALE_THR 8.0f

__device__ __forceinline__ unsigned short f2bf(float f) {
    unsigned int u = __builtin_bit_cast(unsigned int, f);
    u += 0x7FFFu + ((u >> 16) & 1u);   // RNE
    return (unsigned short)(u >> 16);
}
__device__ __forceinline__ u32 pkbf2(float lo, float hi) {
    return (u32)f2bf(lo) | ((u32)f2bf(hi) << 16);
}
__device__ __forceinline__ unsigned short f2h(float f) {
    _Float16 h = (_Float16)f;
    return __builtin_bit_cast(unsigned short, h);
}
__device__ __forceinline__ float h2f(unsigned short u) {
    return (float)__builtin_bit_cast(_Float16, u);
}

// global -> LDS direct (16B per lane, linear dest).
typedef __attribute__((address_space(3))) u32 lds_u32;
typedef __attribute__((address_space(1))) const u32 glb_u32;
__device__ __forceinline__ void gload16(const unsigned short* g, const unsigned short* l) {
    __builtin_amdgcn_global_load_lds((glb_u32*)(uintptr_t)g,
                                     (lds_u32*)(u32)(uintptr_t)l, 16, 0, 0);
}

#define FENCE() __asm__ volatile("" ::: "memory")

// ---------------------------------------------------------------------------
// Kernel 0: convert x and Wq/Wk/Wv fp32 -> bf16 once.
// ---------------------------------------------------------------------------
__global__ __launch_bounds__(256, 8) void xcvt_kernel(
    const float* __restrict__ x, const float* __restrict__ Wq,
    const float* __restrict__ Wk, const float* __restrict__ Wv,
    unsigned short* __restrict__ xb, unsigned short* __restrict__ Wb)
{
    const int gid = blockIdx.x*256 + threadIdx.x;
    const float* src;
    unsigned short* dst;
    size_t off;
    if (gid < 524288) {                 // x: 4,194,304 elems
        src = x; dst = xb; off = (size_t)gid * 8;
    } else {                            // W: 3 x 65,536 elems
        size_t wi = (size_t)(gid - 524288) * 8;
        int w = (int)(wi >> 16);
        off = wi & 65535;
        src = (w == 0) ? Wq : (w == 1) ? Wk : Wv;
        dst = Wb + (size_t)w * 65536;
    }
    const float4 v0 = *(const float4*)(src + off);
    const float4 v1 = *(const float4*)(src + off + 4);
    union { unsigned short u[8]; s16x8 v; } o;
    o.u[0]=f2bf(v0.x); o.u[1]=f2bf(v0.y); o.u[2]=f2bf(v0.z); o.u[3]=f2bf(v0.w);
    o.u[4]=f2bf(v1.x); o.u[5]=f2bf(v1.y); o.u[6]=f2bf(v1.z); o.u[7]=f2bf(v1.w);
    *(s16x8*)(dst + off) = o.v;
}

// ---------------------------------------------------------------------------
// Kernel 1: QKV projection (bf16 in, bf16 out).  Grid 512; 2 blocks/CU.
// ---------------------------------------------------------------------------
#define PWSTR 264

__global__ __launch_bounds__(256, 2) void proj_kernel(
    const unsigned short* __restrict__ xb, const unsigned short* __restrict__ Wb,
    unsigned short* __restrict__ Qb, unsigned short* __restrict__ Kb,
    unsigned short* __restrict__ Vt)
{
    __shared__ unsigned short Wl[3][32][PWSTR];  // 50688 B
    __shared__ unsigned short QKs[2][64][40];    // 10240 B
    __shared__ unsigned short Vtr[32][72];       //  4608 B
    const int bid = blockIdx.x;
    const int ct  = bid >> 6;   // 0..7: 32 out-cols
    const int rb  = bid & 63;   // 256-row group
    const int t   = threadIdx.x;

    {   // stage 32x256 bf16 chunk of each W
        const int o = t >> 3, seg = t & 7;
        #pragma unroll
        for (int w = 0; w < 3; ++w) {
            const unsigned short* src = Wb + (size_t)w*65536 + (ct*32 + o)*256 + seg*32;
            #pragma unroll
            for (int i = 0; i < 4; ++i)
                *(s16x8*)&Wl[w][o][seg*32 + i*8] = *(const s16x8*)(src + i*8);
        }
    }
    __syncthreads();

    const int wave = t >> 6, lane = t & 63;
    const int g = lane >> 4, lr = lane & 15;

    for (int it = 0; it < 4; ++it) {
        const int rowblk = rb*256 + it*64;
        const int rowbase = rowblk + wave*16;
        s16x8 a[8];
        {
            const unsigned short* xr = xb + (size_t)(rowbase + lr)*256;
            #pragma unroll
            for (int c = 0; c < 8; ++c)
                a[c] = *(const s16x8*)(xr + c*32 + g*8);
        }
        f32x4 acc[3][2];
        #pragma unroll
        for (int w = 0; w < 3; ++w)
            #pragma unroll
            for (int cf = 0; cf < 2; ++cf)
                #pragma unroll
                for (int j = 0; j < 4; ++j) acc[w][cf][j] = 0.0f;

        #pragma unroll
        for (int w = 0; w < 3; ++w)
            #pragma unroll
            for (int cf = 0; cf < 2; ++cf)
                #pragma unroll
                for (int c = 0; c < 8; ++c) {
                    s16x8 bfr = *(const s16x8*)&Wl[w][cf*16 + lr][c*32 + g*8];
                    acc[w][cf] = __builtin_amdgcn_mfma_f32_16x16x32_bf16(a[c], bfr, acc[w][cf], 0, 0, 0);
                }

        __syncthreads();
        #pragma unroll
        for (int cf = 0; cf < 2; ++cf) {
            #pragma unroll
            for (int j = 0; j < 4; ++j) {
                const int row = wave*16 + g*4 + j;
                QKs[0][row][cf*16 + lr] = f2bf(acc[0][cf][j] * 0.0625f);  // fold 1/sqrt(256)
                QKs[1][row][cf*16 + lr] = f2bf(acc[1][cf][j]);
            }
            ushort4 pv;
            pv.x = f2bf(acc[2][cf][0]); pv.y = f2bf(acc[2][cf][1]);
            pv.z = f2bf(acc[2][cf][2]); pv.w = f2bf(acc[2][cf][3]);
            *(ushort4*)&Vtr[cf*16 + lr][wave*16 + g*4] = pv;
        }
        __syncthreads();
        {   // coalesced b128 stores
            const int row = t >> 2, cs = t & 3;
            *(s16x8*)&Qb[(size_t)(rowblk + row)*256 + ct*32 + cs*8] = *(const s16x8*)&QKs[0][row][cs*8];
            *(s16x8*)&Kb[(size_t)(rowblk + row)*256 + ct*32 + cs*8] = *(const s16x8*)&QKs[1][row][cs*8];
            const int colL = t >> 3, seg = t & 7;
            const int bb = rowblk >> 12, ss0 = rowblk & 4095;
            *(s16x8*)&Vt[((size_t)(bb*256 + ct*32 + colL))*4096 + ss0 + seg*8] = *(const s16x8*)&Vtr[colL][seg*8];
        }
    }
}

// ---------------------------------------------------------------------------
// Kernel 2: flash attention, split-KV H=4.  Grid 512 = 16 (b,h) XCD-pinned
// groups x 32 q-tiles(128).  512 threads = 8 waves (4 qh x 2 kvh); 67KB LDS ->
// 2 blocks/CU (16 waves/CU) WITHOUT a VGPR cap: launch_bounds min-waves stays
// at 2 (R9's 4 forced a 64-VGPR cap -> accumulator spill -> 2.4GB scratch
// traffic/dispatch).  Single K buf + single V buf, rotating counted-vmcnt
// schedule.  In-block kvh merge; f16 partials -> 4-way combine.
// ---------------------------------------------------------------------------
#define AKVB 64
#define ANT  16          // 1024 kv per block / 64

__global__ __launch_bounds__(512, 2) void attn_kernel(
    const unsigned short* __restrict__ Qb, const unsigned short* __restrict__ Kb,
    const unsigned short* __restrict__ Vt, unsigned short* __restrict__ pob,
    float* __restrict__ pm, float* __restrict__ pl)
{
    __shared__ unsigned short KV[32768];   // K: [64][256] @0 ; V: [256][64] @16384 (elems)
    __shared__ float All[8][32];
    __shared__ float MrgM[128], MrgL[128], Wt1[128], Wt2[128];

    const int bid = blockIdx.x;
    const int grp = bid & 15;                // grp&7 = XCD pin (2 groups/XCD)
    const int b = grp >> 2, h = grp & 3;
    const int qt = bid >> 4;
    const int t = threadIdx.x;
    const int w = t >> 6, lane = t & 63;
    const int h8 = lane >> 5, lr5 = lane & 31;
    const int qh = w >> 1, kvh = w & 1;
    const int kv0 = h * 1024;
    const int rowbase = b*4096 + qt*128 + qh*32;

    const unsigned short* Kg = Kb + (size_t)b*4096*256;
    const unsigned short* Vg = Vt + (size_t)b*256*4096;

    // Q B-fragments: col = q = lr5, k = mi*16 + h8*8 + j
    s16x8 qa[16];
    {
        const unsigned short* qp = Qb + (size_t)(rowbase + lr5)*256;
        #pragma unroll
        for (int mi = 0; mi < 16; ++mi)
            qa[mi] = *(const s16x8*)(qp + mi*16 + h8*8);
    }

    f32x16 acc[8];
    #pragma unroll
    for (int cc = 0; cc < 8; ++cc)
        #pragma unroll
        for (int r = 0; r < 16; ++r) acc[cc][r] = 0.0f;
    float m = -__builtin_inff(), l = 0.0f;   // per-lane state for q = lr5

    auto stageK = [&](int kt2) {
        const int kvb = kv0 + kt2*AKVB;
        #pragma unroll
        for (int i = 0; i < 4; ++i) {
            const int idx = i*512 + t;
            const int kr = idx >> 5, ks = idx & 31;          // 64 rows x 32 slots
            gload16(Kg + (size_t)(kvb + kr)*256 + ((ks ^ (kr & 31)) << 3),
                    &KV[idx << 3]);
        }
    };
    auto stageV = [&](int kt2) {
        const int kvb = kv0 + kt2*AKVB;
        #pragma unroll
        for (int i = 0; i < 4; ++i) {
            const int idx = i*512 + t;
            const int vr = idx >> 3, vs = idx & 7;           // 256 rows x 8 slots
            gload16(Vg + (size_t)vr*4096 + kvb + ((vs ^ (vr & 7)) << 3),
                    &KV[16384 + (idx << 3)]);
        }
    };

    stageK(0);
    stageV(0);

    for (int kt = 0; kt < ANT; ++kt) {
        const bool last = (kt == ANT - 1);

        // wait own K(kt) loads (V(kt) stays in flight), sync all waves
        __asm__ volatile("s_waitcnt vmcnt(4)" ::: "memory");
        __builtin_amdgcn_s_barrier();
        FENCE();

        // Swapped QK^T: A = K rows, B = Q.  C: col=q=lr5, row=kv=(r&3)+8(r>>2)+4h8.
        const int krow = kvh*32 + lr5;
        const int ksw = krow & 31;
        f32x16 sc;
        #pragma unroll
        for (int r = 0; r < 16; ++r) sc[r] = 0.0f;
        __builtin_amdgcn_s_setprio(1);
        #pragma unroll
        for (int mi = 0; mi < 16; ++mi) {
            const int slot = (2*mi + h8) ^ ksw;
            s16x8 kf = *(const s16x8*)&KV[krow*256 + slot*8];
            sc = __builtin_amdgcn_mfma_f32_32x32x16_bf16(kf, qa[mi], sc, 0, 0, 0);
        }
        __builtin_amdgcn_s_setprio(0);

        // all waves done reading K buf -> start refilling it
        __builtin_amdgcn_s_barrier();
        FENCE();
        if (!last) stageK(kt + 1);

        // softmax overlaps the K(kt+1)/V(kt) flight
        float x0 = fmaxf(sc[0],  sc[1]),  x1 = fmaxf(sc[2],  sc[3]);
        float x2 = fmaxf(sc[4],  sc[5]),  x3 = fmaxf(sc[6],  sc[7]);
        float x4 = fmaxf(sc[8],  sc[9]),  x5 = fmaxf(sc[10], sc[11]);
        float x6 = fmaxf(sc[12], sc[13]), x7 = fmaxf(sc[14], sc[15]);
        x0 = fmaxf(x0, x1); x2 = fmaxf(x2, x3); x4 = fmaxf(x4, x5); x6 = fmaxf(x6, x7);
        float pmax = fmaxf(fmaxf(x0, x2), fmaxf(x4, x6));
        pmax = fmaxf(pmax, __shfl_xor(pmax, 32));

        if (!__all(pmax - m <= RESCALE_THR)) {
            const float mn = fmaxf(m, pmax);
            const float al = __builtin_amdgcn_exp2f((m - mn) * LOG2E);
            m = mn; l *= al;
            if (lane < 32) All[w][lr5] = al;     // bridge q-col -> q-row layout
            #pragma unroll
            for (int rr = 0; rr < 4; ++rr) {
                f32x4 a4 = *(const f32x4*)&All[w][rr*8 + 4*h8];
                #pragma unroll
                for (int rj = 0; rj < 4; ++rj)
                    #pragma unroll
                    for (int cc = 0; cc < 8; ++cc) acc[cc][rr*4 + rj] *= a4[rj];
            }
        }

        #pragma unroll
        for (int r = 0; r < 16; ++r) sc[r] = __builtin_amdgcn_exp2f((sc[r] - m) * LOG2E);
        float ps = ((sc[0]+sc[1]) + (sc[2]+sc[3])) + ((sc[4]+sc[5]) + (sc[6]+sc[7]))
                 + ((sc[8]+sc[9]) + (sc[10]+sc[11])) + ((sc[12]+sc[13]) + (sc[14]+sc[15]));
        ps += __shfl_xor(ps, 32);
        l += ps;

        // P -> A-fragments in-register (half-exchange via shfl_xor 32)
        const u32 dw0 = pkbf2(sc[0],  sc[1]),  dw1 = pkbf2(sc[2],  sc[3]);
        const u32 dw2 = pkbf2(sc[4],  sc[5]),  dw3 = pkbf2(sc[6],  sc[7]);
        const u32 dw4 = pkbf2(sc[8],  sc[9]),  dw5 = pkbf2(sc[10], sc[11]);
        const u32 dw6 = pkbf2(sc[12], sc[13]), dw7 = pkbf2(sc[14], sc[15]);
        const bool hi = (h8 != 0);
        const u32 s10 = __shfl_xor(hi ? dw0 : dw2, 32);
        const u32 s11 = __shfl_xor(hi ? dw1 : dw3, 32);
        const u32 s20 = __shfl_xor(hi ? dw4 : dw6, 32);
        const u32 s21 = __shfl_xor(hi ? dw5 : dw7, 32);
        union { u32 u[4]; s16x8 v; } pa1, pa2;
        pa1.u[0] = hi ? s10 : dw0;  pa1.u[1] = hi ? s11 : dw1;
        pa1.u[2] = hi ? dw2 : s10;  pa1.u[3] = hi ? dw3 : s11;
        pa2.u[0] = hi ? s20 : dw4;  pa2.u[1] = hi ? s21 : dw5;
        pa2.u[2] = hi ? dw6 : s20;  pa2.u[3] = hi ? dw7 : s21;

        // wait own V(kt) loads (K(kt+1) stays in flight), sync
        if (!last) { __asm__ volatile("s_waitcnt vmcnt(4)" ::: "memory"); }
        else       { __asm__ volatile("s_waitcnt vmcnt(0)" ::: "memory"); }
        __builtin_amdgcn_s_barrier();
        FENCE();

        // PV: out[32q][256d] += P[32q x 32kv] * V[32kv x d]
        __builtin_amdgcn_s_setprio(1);
        #pragma unroll
        for (int cc = 0; cc < 8; ++cc) {
            const int vrow = cc*32 + lr5;
            const int vsw = vrow & 7;
            s16x8 v1 = *(const s16x8*)&KV[16384 + vrow*64 + (((4*kvh + h8)     ^ vsw) << 3)];
            s16x8 v2 = *(const s16x8*)&KV[16384 + vrow*64 + (((4*kvh + 2 + h8) ^ vsw) << 3)];
            acc[cc] = __builtin_amdgcn_mfma_f32_32x32x16_bf16(pa1.v, v1, acc[cc], 0, 0, 0);
            acc[cc] = __builtin_amdgcn_mfma_f32_32x32x16_bf16(pa2.v, v2, acc[cc], 0, 0, 0);
        }
        __builtin_amdgcn_s_setprio(0);

        if (!last) {            // all done reading V buf -> refill it
            __builtin_amdgcn_s_barrier();
            FENCE();
            stageV(kt + 1);
        }
    }

    // ---- in-block merge of kvh halves (reuse KV as [64][256] f32, 2 chunks) ----
    __syncthreads();
    float* Mrg = (float*)&KV[0];
    for (int half = 0; half < 2; ++half) {
        if (kvh == 1 && (qh >> 1) == half) {
            const int qs = (qh & 1) << 5;
            #pragma unroll
            for (int cc = 0; cc < 8; ++cc)
                #pragma unroll
                for (int r = 0; r < 16; ++r) {
                    const int qr = (r & 3) + 8*(r >> 2) + 4*h8;
                    Mrg[(qs + qr)*256 + cc*32 + lr5] = acc[cc][r];
                }
            if (lane < 32) { MrgM[qh*32 + lr5] = m; MrgL[qh*32 + lr5] = l; }
        }
        __syncthreads();
        if (kvh == 0 && (qh >> 1) == half) {
            const int qs = (qh & 1) << 5;
            const float m2 = MrgM[qh*32 + lr5], l2 = MrgL[qh*32 + lr5];
            const float M  = fmaxf(m, m2);
            const float w1 = __builtin_amdgcn_exp2f((m  - M) * LOG2E);
            const float w2 = __builtin_amdgcn_exp2f((m2 - M) * LOG2E);
            const float L  = l*w1 + l2*w2;
            const float r1 = w1 / L, r2 = w2 / L;
            if (lane < 32) {
                Wt1[qh*32 + lr5] = r1; Wt2[qh*32 + lr5] = r2;
                pm[(size_t)h*NROW + rowbase + lr5] = M;
                pl[(size_t)h*NROW + rowbase + lr5] = L;
            }
            unsigned short* pd = pob + (size_t)h*NROW*256;
            #pragma unroll
            for (int rr = 0; rr < 4; ++rr) {
                f32x4 r1q = *(const f32x4*)&Wt1[qh*32 + rr*8 + 4*h8];
                f32x4 r2q = *(const f32x4*)&Wt2[qh*32 + rr*8 + 4*h8];
                #pragma unroll
                for (int rj = 0; rj < 4; ++rj) {
                    const int qr = rj + 8*rr + 4*h8;
                    #pragma unroll
                    for (int cc = 0; cc < 8; ++cc) {
                        const float v = acc[cc][rr*4 + rj]*r1q[rj]
                                      + Mrg[(qs + qr)*256 + cc*32 + lr5]*r2q[rj];
                        pd[(size_t)(rowbase + qr)*256 + cc*32 + lr5] = f2h(v);
                    }
                }
            }
        }
        __syncthreads();
    }
}

// ---------------------------------------------------------------------------
// Kernel 3: combine the four KV-quarter partials (normalized f16 O + m,l).
// ---------------------------------------------------------------------------
__global__ __launch_bounds__(256, 8) void combine_kernel(
    const unsigned short* __restrict__ pob, const float* __restrict__ pm,
    const float* __restrict__ pl, float* __restrict__ out)
{
    const int idx = blockIdx.x*256 + threadIdx.x;   // grid 2048 -> 524288 threads
    const int row = idx >> 5;
    const int d8 = (idx & 31) << 3;
    const float M = fmaxf(fmaxf(pm[row], pm[NROW + row]),
                          fmaxf(pm[2*NROW + row], pm[3*NROW + row]));
    float o[8] = {0,0,0,0,0,0,0,0};
    float wsum = 0.0f;
    #pragma unroll
    for (int i = 0; i < 4; ++i) {
        const float wgt = __builtin_amdgcn_exp2f((pm[i*NROW + row] - M) * LOG2E)
                        * pl[i*NROW + row];
        wsum += wgt;
        s16x8 v = *(const s16x8*)(pob + (size_t)i*NROW*256 + (size_t)row*256 + d8);
        #pragma unroll
        for (int j = 0; j < 8; ++j)
            o[j] += wgt * h2f((unsigned short)v[j]);
    }
    const float r = 1.0f / wsum;
    float4 o0 = {o[0]*r, o[1]*r, o[2]*r, o[3]*r};
    float4 o1 = {o[4]*r, o[5]*r, o[6]*r, o[7]*r};
    *(float4*)(out + (size_t)row*256 + d8)     = o0;
    *(float4*)(out + (size_t)row*256 + d8 + 4) = o1;
}

// ---------------------------------------------------------------------------
extern "C" void kernel_launch(void* const* d_in, const int* in_sizes, int n_in,
                              void* d_out, int out_size, void* d_ws, size_t ws_size,
                              hipStream_t stream) {
    const float* x  = (const float*)d_in[0];
    const float* Wq = (const float*)d_in[1];
    const float* Wk = (const float*)d_in[2];
    const float* Wv = (const float*)d_in[3];

    unsigned short* Qb  = (unsigned short*)d_ws;         // 8 MB
    unsigned short* Kb  = Qb + (size_t)NROW*EMB;         // 8 MB
    unsigned short* Vt  = Kb + (size_t)NROW*EMB;         // 8 MB, [b][d][s]
    unsigned short* pob = Vt + (size_t)NROW*EMB;         // 32 MB, f16 [4][NROW][256]
    float* pm = (float*)(pob + (size_t)4*NROW*EMB);      // 256 KB
    float* pl = pm + (size_t)4*NROW;                     // 256 KB  (total ~56.5 MB)
    // xb (8.4MB) + Wb alias pob (dead after proj; pob written by attn)
    unsigned short* xb = pob;
    unsigned short* Wb = xb + (size_t)NROW*EMB;

    xcvt_kernel<<<2144, 256, 0, stream>>>(x, Wq, Wk, Wv, xb, Wb);
    proj_kernel<<<512, 256, 0, stream>>>(xb, Wb, Qb, Kb, Vt);
    attn_kernel<<<512, 512, 0, stream>>>(Qb, Kb, Vt, pob, pm, pl);
    combine_kernel<<<2048, 256, 0, stream>>>(pob, pm, pl, (float*)d_out);
}